// Round 1
// baseline (2453.791 us; speedup 1.0000x reference)
//
#include <hip/hip_runtime.h>
#include <math.h>

#define SEQ 2048
#define DMODEL 1024
#define NH 16
#define DK 64
#define BATCH 2

// ---------------------------------------------------------------------------
// GEMM NT: C[m,n] = sum_k X[m,k] * W[n,k];  M=4096, N=1024, K=1024.
// permute==1: store into [B, H, S, DK] layout (QKV projections)
// permute==0: store plain row-major [M, N]
// 64x64 tile, 256 threads, 4x4 register tile, K-tile 16, LDS k-major pad 68.
// ---------------------------------------------------------------------------
__global__ __launch_bounds__(256) void gemm_nt(const float* __restrict__ X,
                                               const float* __restrict__ W,
                                               float* __restrict__ out,
                                               int permute) {
    __shared__ float As[16][68];
    __shared__ float Bs[16][68];
    const int t  = threadIdx.x;
    const int tx = t & 15, ty = t >> 4;
    const int m0 = blockIdx.y * 64, n0 = blockIdx.x * 64;
    const int lr = t >> 2;          // 0..63 row within tile
    const int lk = (t & 3) << 2;    // 0,4,8,12 k within tile

    float acc[4][4] = {};

    for (int k0 = 0; k0 < 1024; k0 += 16) {
        float4 av = *(const float4*)(X + (size_t)(m0 + lr) * 1024 + k0 + lk);
        float4 bv = *(const float4*)(W + (size_t)(n0 + lr) * 1024 + k0 + lk);
        __syncthreads();   // protect previous iteration's reads
        As[lk + 0][lr] = av.x; As[lk + 1][lr] = av.y;
        As[lk + 2][lr] = av.z; As[lk + 3][lr] = av.w;
        Bs[lk + 0][lr] = bv.x; Bs[lk + 1][lr] = bv.y;
        Bs[lk + 2][lr] = bv.z; Bs[lk + 3][lr] = bv.w;
        __syncthreads();
#pragma unroll
        for (int kk = 0; kk < 16; ++kk) {
            float4 a = *(const float4*)&As[kk][ty * 4];
            float4 b = *(const float4*)&Bs[kk][tx * 4];
            acc[0][0] += a.x * b.x; acc[0][1] += a.x * b.y; acc[0][2] += a.x * b.z; acc[0][3] += a.x * b.w;
            acc[1][0] += a.y * b.x; acc[1][1] += a.y * b.y; acc[1][2] += a.y * b.z; acc[1][3] += a.y * b.w;
            acc[2][0] += a.z * b.x; acc[2][1] += a.z * b.y; acc[2][2] += a.z * b.z; acc[2][3] += a.z * b.w;
            acc[3][0] += a.w * b.x; acc[3][1] += a.w * b.y; acc[3][2] += a.w * b.z; acc[3][3] += a.w * b.w;
        }
    }

#pragma unroll
    for (int i = 0; i < 4; ++i) {
        int m = m0 + ty * 4 + i;
        int n = n0 + tx * 4;
        float4 v = make_float4(acc[i][0], acc[i][1], acc[i][2], acc[i][3]);
        if (permute) {
            int b = m >> 11, s = m & 2047;
            int h = n >> 6,  d = n & 63;
            *(float4*)(out + ((((size_t)b * NH + h) * SEQ + s) * DK + d)) = v;
        } else {
            *(float4*)(out + (size_t)m * 1024 + n) = v;
        }
    }
}

// ---------------------------------------------------------------------------
// Attention: block = (q-tile of 8 rows, batch b); loops all 16 heads.
// 512 threads = 8 waves; wave w owns q-row w (softmax = wave shuffle reduce).
// LDS: sc[8][2048] fp32 scores (64KB) + kv[256*68] staging buffer (69.6KB).
// avg_attention accumulated via exclusive global RMW (block owns its rows).
// ---------------------------------------------------------------------------
__global__ __launch_bounds__(512) void attn_kernel(const float* __restrict__ Qp,
                                                   const float* __restrict__ Kp,
                                                   const float* __restrict__ Vp,
                                                   float* __restrict__ att,
                                                   float* __restrict__ avg) {
    __shared__ float sc[8][SEQ];      // 64 KB
    __shared__ float kv[256 * 68];    // 69.6 KB (K tiles / V tiles / reduce scratch)

    const int t    = threadIdx.x;
    const int q0   = blockIdx.x * 8;
    const int b    = blockIdx.y;
    const int w    = t >> 6;          // wave id == local q row
    const int lane = t & 63;

    for (int h = 0; h < NH; ++h) {
        // ---- Q row of this wave into registers (broadcast loads) ----
        const float* Qrow = Qp + (((size_t)b * NH + h) * SEQ + q0 + w) * DK;
        float4 qr[16];
#pragma unroll
        for (int i = 0; i < 16; ++i) qr[i] = *(const float4*)(Qrow + i * 4);

        const float* Kh = Kp + ((size_t)b * NH + h) * SEQ * DK;
        const float* Vh = Vp + ((size_t)b * NH + h) * SEQ * DK;

        // ---- scores: sc[w][k] = (Q_w . K_k) / 8 ----
        for (int k0 = 0; k0 < SEQ; k0 += 256) {
            __syncthreads();   // protect previous use of kv
#pragma unroll
            for (int i = 0; i < 8; ++i) {
                int idx = i * 512 + t;          // float4 units: 256 rows x 16
                int row = idx >> 4, c4 = (idx & 15) << 2;
                *(float4*)&kv[row * 68 + c4] =
                    *(const float4*)(Kh + (size_t)(k0 + row) * DK + c4);
            }
            __syncthreads();
            float s0 = 0.f, s1 = 0.f, s2 = 0.f, s3 = 0.f;
            const int kb = lane;
#pragma unroll
            for (int d4 = 0; d4 < 16; ++d4) {
                float4 qv = qr[d4];
                float4 k0v = *(const float4*)&kv[(kb      ) * 68 + d4 * 4];
                float4 k1v = *(const float4*)&kv[(kb +  64) * 68 + d4 * 4];
                float4 k2v = *(const float4*)&kv[(kb + 128) * 68 + d4 * 4];
                float4 k3v = *(const float4*)&kv[(kb + 192) * 68 + d4 * 4];
                s0 += qv.x * k0v.x + qv.y * k0v.y + qv.z * k0v.z + qv.w * k0v.w;
                s1 += qv.x * k1v.x + qv.y * k1v.y + qv.z * k1v.z + qv.w * k1v.w;
                s2 += qv.x * k2v.x + qv.y * k2v.y + qv.z * k2v.z + qv.w * k2v.w;
                s3 += qv.x * k3v.x + qv.y * k3v.y + qv.z * k3v.z + qv.w * k3v.w;
            }
            sc[w][k0 + kb      ] = s0 * 0.125f;
            sc[w][k0 + kb +  64] = s1 * 0.125f;
            sc[w][k0 + kb + 128] = s2 * 0.125f;
            sc[w][k0 + kb + 192] = s3 * 0.125f;
        }

        // ---- softmax over row w (wave-local; each lane touches only its own elems) ----
        float mx = -1e30f;
        for (int j = lane; j < SEQ; j += 64) mx = fmaxf(mx, sc[w][j]);
#pragma unroll
        for (int off = 32; off > 0; off >>= 1) mx = fmaxf(mx, __shfl_xor(mx, off, 64));
        float sum = 0.f;
        for (int j = lane; j < SEQ; j += 64) {
            float e = __expf(sc[w][j] - mx);
            sc[w][j] = e;
            sum += e;
        }
#pragma unroll
        for (int off = 32; off > 0; off >>= 1) sum += __shfl_xor(sum, off, 64);
        const float inv = 1.0f / sum;

        // ---- normalize + head-mean accumulation (exclusive RMW, no atomics) ----
        float* avgrow = avg + ((size_t)b * SEQ + q0 + w) * SEQ;
        for (int j = lane; j < SEQ; j += 64) {
            float p = sc[w][j] * inv;
            sc[w][j] = p;
            float contrib = p * (1.0f / NH);
            if (h == 0) avgrow[j] = contrib;     // d_out is poisoned: first head stores
            else        avgrow[j] += contrib;
        }

        // ---- PV: attended[w][d] = sum_k p[w][k] * V[k][d] ----
        const int d4 = (t & 15) << 2;       // output col group (4 floats)
        const int ks = (t >> 4) & 3;        // k stripe within tile
        float4 acc = make_float4(0.f, 0.f, 0.f, 0.f);
        for (int k0 = 0; k0 < SEQ; k0 += 256) {
            __syncthreads();
#pragma unroll
            for (int i = 0; i < 8; ++i) {
                int idx = i * 512 + t;
                int row = idx >> 4, c4 = (idx & 15) << 2;
                *(float4*)&kv[row * 68 + c4] =
                    *(const float4*)(Vh + (size_t)(k0 + row) * DK + c4);
            }
            __syncthreads();
#pragma unroll 8
            for (int j = 0; j < 64; ++j) {
                int k = ks * 64 + j;
                float  p = sc[w][k0 + k];
                float4 v = *(const float4*)&kv[k * 68 + d4];
                acc.x += p * v.x; acc.y += p * v.y;
                acc.z += p * v.z; acc.w += p * v.w;
            }
        }
        // reduce the 4 k-stripe partials via LDS (reuse kv buffer)
        __syncthreads();
        *(float4*)&kv[t * 4] = acc;
        __syncthreads();
        if (t < 128) {
            int q = t >> 4, dd = (t & 15) << 2;
            float4 r0 = *(const float4*)&kv[((q * 64) + 0 * 16 + (t & 15)) * 4];
            float4 r1 = *(const float4*)&kv[((q * 64) + 1 * 16 + (t & 15)) * 4];
            float4 r2 = *(const float4*)&kv[((q * 64) + 2 * 16 + (t & 15)) * 4];
            float4 r3 = *(const float4*)&kv[((q * 64) + 3 * 16 + (t & 15)) * 4];
            float4 o = make_float4(r0.x + r1.x + r2.x + r3.x,
                                   r0.y + r1.y + r2.y + r3.y,
                                   r0.z + r1.z + r2.z + r3.z,
                                   r0.w + r1.w + r2.w + r3.w);
            *(float4*)(att + ((size_t)b * SEQ + q0 + q) * DMODEL + h * DK + dd) = o;
        }
    }
}

// ---------------------------------------------------------------------------
extern "C" void kernel_launch(void* const* d_in, const int* in_sizes, int n_in,
                              void* d_out, int out_size, void* d_ws, size_t ws_size,
                              hipStream_t stream) {
    const float* query = (const float*)d_in[0];
    const float* key   = (const float*)d_in[1];
    const float* value = (const float*)d_in[2];
    const float* w_q   = (const float*)d_in[3];
    const float* w_k   = (const float*)d_in[4];
    const float* w_v   = (const float*)d_in[5];
    const float* w_o   = (const float*)d_in[6];

    float* out = (float*)d_out;                         // [B,S,D] = 4,194,304 floats
    float* avg = out + (size_t)BATCH * SEQ * DMODEL;    // [B,S,S] = 8,388,608 floats

    float* ws = (float*)d_ws;
    float* Qp = ws;                       // [B,H,S,DK]  4,194,304 floats
    float* Kp = ws + 4194304;             // [B,H,S,DK]
    float* Vp = ws + 8388608;             // [B,H,S,DK]
    float* At = ws + 12582912;            // [B,S,D] attended (head-major inner)

    dim3 gg(16, 64);   // N/64, M/64
    gemm_nt<<<gg, 256, 0, stream>>>(query, w_q, Qp, 1);
    gemm_nt<<<gg, 256, 0, stream>>>(key,   w_k, Kp, 1);
    gemm_nt<<<gg, 256, 0, stream>>>(value, w_v, Vp, 1);

    attn_kernel<<<dim3(SEQ / 8, BATCH), 512, 0, stream>>>(Qp, Kp, Vp, At, avg);

    gemm_nt<<<gg, 256, 0, stream>>>(At, w_o, out, 0);
}

// Round 2
// 842.236 us; speedup vs baseline: 2.9134x; 2.9134x over previous
//
#include <hip/hip_runtime.h>
#include <math.h>

#define SEQ 2048
#define DMODEL 1024
#define NH 16
#define DK 64
#define BATCH 2

using bf16x8 = __attribute__((ext_vector_type(8))) __bf16;
using bf16x4 = __attribute__((ext_vector_type(4))) __bf16;
using f32x4  = __attribute__((ext_vector_type(4))) float;

__device__ inline f32x4 mfma16(bf16x8 a, bf16x8 b, f32x4 c) {
    return __builtin_amdgcn_mfma_f32_16x16x32_bf16(a, b, c, 0, 0, 0);
}

// ---------------------------------------------------------------------------
// GEMM NT: C[m,n] = dot(X[m,:], W[n,:]); K=1024 fixed; M,N from grid.
// mode 0: fp32 out [M,N]
// mode 1: bf16 out [b][h][s][dk]   (m -> b,s ; n -> h,dk)   — Q,K projections
// mode 2: bf16 out [b][h][dk][s]   (m -> h,dk ; n -> b,s)   — V^T projection
// ---------------------------------------------------------------------------
__global__ __launch_bounds__(256) void gemm_nt(const float* __restrict__ X,
                                               const float* __restrict__ W,
                                               void* __restrict__ out,
                                               int mode) {
    __shared__ float As[16][68];
    __shared__ float Bs[16][68];
    const int t  = threadIdx.x;
    const int tx = t & 15, ty = t >> 4;
    const int m0 = blockIdx.y * 64, n0 = blockIdx.x * 64;
    const int lr = t >> 2;
    const int lk = (t & 3) << 2;

    float acc[4][4] = {};

    for (int k0 = 0; k0 < 1024; k0 += 16) {
        float4 av = *(const float4*)(X + (size_t)(m0 + lr) * 1024 + k0 + lk);
        float4 bv = *(const float4*)(W + (size_t)(n0 + lr) * 1024 + k0 + lk);
        __syncthreads();
        As[lk + 0][lr] = av.x; As[lk + 1][lr] = av.y;
        As[lk + 2][lr] = av.z; As[lk + 3][lr] = av.w;
        Bs[lk + 0][lr] = bv.x; Bs[lk + 1][lr] = bv.y;
        Bs[lk + 2][lr] = bv.z; Bs[lk + 3][lr] = bv.w;
        __syncthreads();
#pragma unroll
        for (int kk = 0; kk < 16; ++kk) {
            float4 a = *(const float4*)&As[kk][ty * 4];
            float4 b = *(const float4*)&Bs[kk][tx * 4];
            acc[0][0] += a.x * b.x; acc[0][1] += a.x * b.y; acc[0][2] += a.x * b.z; acc[0][3] += a.x * b.w;
            acc[1][0] += a.y * b.x; acc[1][1] += a.y * b.y; acc[1][2] += a.y * b.z; acc[1][3] += a.y * b.w;
            acc[2][0] += a.z * b.x; acc[2][1] += a.z * b.y; acc[2][2] += a.z * b.z; acc[2][3] += a.z * b.w;
            acc[3][0] += a.w * b.x; acc[3][1] += a.w * b.y; acc[3][2] += a.w * b.z; acc[3][3] += a.w * b.w;
        }
    }

#pragma unroll
    for (int i = 0; i < 4; ++i) {
        int m = m0 + ty * 4 + i;
        int n = n0 + tx * 4;
        if (mode == 0) {
            *(float4*)((float*)out + (size_t)m * 1024 + n) =
                make_float4(acc[i][0], acc[i][1], acc[i][2], acc[i][3]);
        } else {
            bf16x4 v;
            v[0] = (__bf16)acc[i][0]; v[1] = (__bf16)acc[i][1];
            v[2] = (__bf16)acc[i][2]; v[3] = (__bf16)acc[i][3];
            __bf16* ob = (__bf16*)out;
            if (mode == 1) {
                int bb = m >> 11, s = m & 2047, hh = n >> 6, dd = n & 63;
                *(bf16x4*)(ob + ((((size_t)bb * NH + hh) * SEQ + s) * DK + dd)) = v;
            } else {
                int hh = m >> 6, dd = m & 63, bb = n >> 11, s = n & 2047;
                *(bf16x4*)(ob + ((((size_t)bb * NH + hh) * DK + dd) * SEQ + s)) = v;
            }
        }
    }
}

// ---------------------------------------------------------------------------
// MFMA attention. Block = 16 q-rows x one batch, loops all 16 heads.
// 512 threads = 8 waves. Scores in LDS fp32 (stride 2052). avg accumulated
// in 64 VGPRs/thread, written once. A/B frags loaded straight from global
// (Q,K row-major; V transposed) as contiguous 16B/lane.
// ---------------------------------------------------------------------------
__global__ __launch_bounds__(512) void attn_mfma(const __bf16* __restrict__ Qp,
                                                 const __bf16* __restrict__ Kp,
                                                 const __bf16* __restrict__ Vt,
                                                 float* __restrict__ att,
                                                 float* __restrict__ avg) {
    __shared__ float sc[16 * 2052 + 16];   // scores + stats tail
    float* stats = &sc[16 * 2052];

    const int t    = threadIdx.x;
    const int w    = t >> 6;
    const int lane = t & 63;
    const int q0   = blockIdx.x * 16;
    const int b    = blockIdx.y;

    const int m  = lane & 15;   // MFMA row/col index within tile
    const int kg = lane >> 4;   // 0..3 quad

    const int tq = t >> 5;      // avg-accum q row (0..15)
    const int tl = t & 31;      // avg-accum lane within row

    f32x4 avreg[16] = {};       // 16 q-rows x 2048 cols / 512 threads = 64 f32

    for (int h = 0; h < NH; ++h) {
        const __bf16* Qh = Qp + (((size_t)b * NH + h) * SEQ + q0) * DK;
        const __bf16* Kh = Kp + ((size_t)b * NH + h) * SEQ * DK;
        const __bf16* Vh = Vt + ((size_t)b * NH + h) * DK * SEQ;

        // A-frags: Q[16,64] (reused across all n-tiles)
        bf16x8 a0 = *(const bf16x8*)(Qh + m * DK + kg * 8);
        bf16x8 a1 = *(const bf16x8*)(Qh + m * DK + kg * 8 + 32);

        // ---- scores: sc[q][k] = (Q.K)/8 ----
        for (int nt = w; nt < 128; nt += 8) {
            const __bf16* Kt = Kh + (size_t)(nt * 16 + m) * DK + kg * 8;
            bf16x8 b0 = *(const bf16x8*)(Kt);
            bf16x8 b1 = *(const bf16x8*)(Kt + 32);
            f32x4 c = {};
            c = mfma16(a0, b0, c);
            c = mfma16(a1, b1, c);
#pragma unroll
            for (int r = 0; r < 4; ++r)
                sc[(kg * 4 + r) * 2052 + nt * 16 + m] = c[r] * 0.125f;
        }
        __syncthreads();

        // ---- softmax: wave w owns rows 2w, 2w+1; 32 lanes per row ----
        {
            const int q  = 2 * w + (lane >> 5);
            const int li = lane & 31;
            float* row = &sc[q * 2052];
            float mx = -1e30f;
#pragma unroll
            for (int j = 0; j < 16; ++j) {
                f32x4 v = *(const f32x4*)&row[li * 4 + j * 128];
                mx = fmaxf(mx, fmaxf(fmaxf(v[0], v[1]), fmaxf(v[2], v[3])));
            }
#pragma unroll
            for (int off = 16; off > 0; off >>= 1) mx = fmaxf(mx, __shfl_xor(mx, off, 64));
            float sum = 0.f;
#pragma unroll
            for (int j = 0; j < 16; ++j) {
                f32x4 v = *(f32x4*)&row[li * 4 + j * 128];
                v[0] = __expf(v[0] - mx); v[1] = __expf(v[1] - mx);
                v[2] = __expf(v[2] - mx); v[3] = __expf(v[3] - mx);
                *(f32x4*)&row[li * 4 + j * 128] = v;
                sum += v[0] + v[1] + v[2] + v[3];
            }
#pragma unroll
            for (int off = 16; off > 0; off >>= 1) sum += __shfl_xor(sum, off, 64);
            if (li == 0) stats[q] = 1.0f / sum;
        }
        __syncthreads();

        // ---- avg accumulation into registers ----
        {
            const float s = stats[tq] * (1.0f / NH);
            const float* row = &sc[tq * 2052];
#pragma unroll
            for (int j = 0; j < 16; ++j) {
                f32x4 v = *(const f32x4*)&row[tl * 4 + j * 128];
                avreg[j] += v * s;
            }
        }

        // ---- PV: wave w owns k-range [w*256, w*256+256) ----
        f32x4 pv[4] = {};
        {
            const float invm = stats[m];
            const int kw = w * 256;
#pragma unroll
            for (int c8 = 0; c8 < 8; ++c8) {
                const int kb = kw + c8 * 32 + kg * 8;
                f32x4 p0 = *(const f32x4*)&sc[m * 2052 + kb];
                f32x4 p1 = *(const f32x4*)&sc[m * 2052 + kb + 4];
                bf16x8 af;
                af[0] = (__bf16)(p0[0] * invm); af[1] = (__bf16)(p0[1] * invm);
                af[2] = (__bf16)(p0[2] * invm); af[3] = (__bf16)(p0[3] * invm);
                af[4] = (__bf16)(p1[0] * invm); af[5] = (__bf16)(p1[1] * invm);
                af[6] = (__bf16)(p1[2] * invm); af[7] = (__bf16)(p1[3] * invm);
#pragma unroll
                for (int nt = 0; nt < 4; ++nt) {
                    bf16x8 bv = *(const bf16x8*)(Vh + (size_t)(nt * 16 + m) * SEQ + kb);
                    pv[nt] = mfma16(af, bv, pv[nt]);
                }
            }
        }
        __syncthreads();           // all reads of sc (p) complete

        // ---- cross-wave reduce of PV partials via sc (now dead) ----
#pragma unroll
        for (int nt = 0; nt < 4; ++nt)
#pragma unroll
            for (int r = 0; r < 4; ++r)
                sc[(w * 16 + kg * 4 + r) * 64 + nt * 16 + m] = pv[nt][r];
        __syncthreads();
#pragma unroll
        for (int e = 0; e < 2; ++e) {
            int idx = t + e * 512;
            int q = idx >> 6, d = idx & 63;
            float s = 0.f;
#pragma unroll
            for (int ww = 0; ww < 8; ++ww) s += sc[(ww * 16 + q) * 64 + d];
            att[((size_t)b * SEQ + q0 + q) * DMODEL + h * DK + d] = s;
        }
        __syncthreads();           // before next head overwrites sc
    }

    // ---- write avg_attention once ----
    {
        float* dst = avg + ((size_t)b * SEQ + q0 + tq) * SEQ;
#pragma unroll
        for (int j = 0; j < 16; ++j)
            *(f32x4*)&dst[tl * 4 + j * 128] = avreg[j];
    }
}

// ---------------------------------------------------------------------------
extern "C" void kernel_launch(void* const* d_in, const int* in_sizes, int n_in,
                              void* d_out, int out_size, void* d_ws, size_t ws_size,
                              hipStream_t stream) {
    const float* query = (const float*)d_in[0];
    const float* key   = (const float*)d_in[1];
    const float* value = (const float*)d_in[2];
    const float* w_q   = (const float*)d_in[3];
    const float* w_k   = (const float*)d_in[4];
    const float* w_v   = (const float*)d_in[5];
    const float* w_o   = (const float*)d_in[6];

    float* out = (float*)d_out;                        // [B,S,D]
    float* avg = out + (size_t)BATCH * SEQ * DMODEL;   // [B,S,S]

    __bf16* Qb = (__bf16*)d_ws;                        // [B,H,S,DK] bf16
    __bf16* Kb = Qb + (size_t)4194304;                 // [B,H,S,DK] bf16
    __bf16* Vb = Kb + (size_t)4194304;                 // [B,H,DK,S] bf16 (V^T)
    float*  At = (float*)(Vb + (size_t)4194304);       // [B,S,D] fp32 attended

    dim3 gg(16, 64);   // N=1024/64, M=4096/64
    gemm_nt<<<gg, 256, 0, stream>>>(query, w_q, Qb, 1);
    gemm_nt<<<gg, 256, 0, stream>>>(key,   w_k, Kb, 1);
    gemm_nt<<<dim3(64, 16), 256, 0, stream>>>(w_v, value, Vb, 2);  // M=1024, N=4096

    attn_mfma<<<dim3(SEQ / 16, BATCH), 512, 0, stream>>>(Qb, Kb, Vb, At, avg);

    gemm_nt<<<gg, 256, 0, stream>>>(At, w_o, out, 0);
}

// Round 3
// 537.309 us; speedup vs baseline: 4.5668x; 1.5675x over previous
//
#include <hip/hip_runtime.h>
#include <math.h>

#define SEQ 2048
#define DMODEL 1024
#define NH 16
#define DK 64
#define BATCH 2

using bf16x8 = __attribute__((ext_vector_type(8))) __bf16;
using bf16x4 = __attribute__((ext_vector_type(4))) __bf16;
using f32x4  = __attribute__((ext_vector_type(4))) float;

__device__ inline f32x4 mfma16(bf16x8 a, bf16x8 b, f32x4 c) {
    return __builtin_amdgcn_mfma_f32_16x16x32_bf16(a, b, c, 0, 0, 0);
}

__device__ inline void load_lds16(const void* g, void* l) {
    __builtin_amdgcn_global_load_lds(
        (const __attribute__((address_space(1))) void*)g,
        (__attribute__((address_space(3))) void*)l, 16, 0, 0);
}

// ---------------------------------------------------------------------------
// fp32 -> bf16 conversion for the 3 activations (4096x1024) + 4 weights
// (1024x1024). Each block converts 4096 elements.
// ---------------------------------------------------------------------------
__global__ __launch_bounds__(256) void conv_bf16(
        const float* __restrict__ q, const float* __restrict__ k,
        const float* __restrict__ v, const float* __restrict__ wq,
        const float* __restrict__ wk, const float* __restrict__ wv,
        const float* __restrict__ wo,
        __bf16* __restrict__ oq, __bf16* __restrict__ ok, __bf16* __restrict__ ov,
        __bf16* __restrict__ owq, __bf16* __restrict__ owk,
        __bf16* __restrict__ owv, __bf16* __restrict__ owo) {
    int bid = blockIdx.x;
    const float* src;
    __bf16* dst;
    size_t off;
    if (bid < 3072) {
        int ti = bid >> 10;
        src = ti == 0 ? q : (ti == 1 ? k : v);
        dst = ti == 0 ? oq : (ti == 1 ? ok : ov);
        off = (size_t)(bid & 1023) * 4096;
    } else {
        int ti = (bid - 3072) >> 8;
        src = ti == 0 ? wq : (ti == 1 ? wk : (ti == 2 ? wv : wo));
        dst = ti == 0 ? owq : (ti == 1 ? owk : (ti == 2 ? owv : owo));
        off = (size_t)((bid - 3072) & 255) * 4096;
    }
    src += off; dst += off;
    const int t = threadIdx.x;
#pragma unroll
    for (int i = 0; i < 4; ++i) {
        float4 x = *(const float4*)(src + t * 4 + i * 1024);
        bf16x4 y;
        y[0] = (__bf16)x.x; y[1] = (__bf16)x.y;
        y[2] = (__bf16)x.z; y[3] = (__bf16)x.w;
        *(bf16x4*)(dst + t * 4 + i * 1024) = y;
    }
}

// ---------------------------------------------------------------------------
// bf16 MFMA GEMM NT: C[m,n] = dot(A[m,:], B[n,:]), K=1024.
// 128x128 tile, BK=64, 256 threads = 2x2 waves of 64x64 (4x4 MFMA tiles).
// Staging via global_load_lds width=16 into fragment-ordered LDS:
//   block (mt,kt) = 1024B, lane j holds A[mt*16 + (j&15)][kt*32 + (j>>4)*8 ..+8]
// so compute-side ds_read_b128 at base + lane*16 is contiguous (conflict-free).
// mode 0: fp32 out row-major [M][N]   (N = gridDim.x*128)
// mode 1: bf16 out row-major [M][N]
// mode 2: bf16 out Vt layout [b][h][dk][s]  (m->(h,dk), n->(b,s))
// ---------------------------------------------------------------------------
__global__ __launch_bounds__(256) void gemm_bf16(const __bf16* __restrict__ A,
                                                 const __bf16* __restrict__ B,
                                                 void* __restrict__ out,
                                                 int mode) {
    __shared__ __align__(16) __bf16 As[8192];   // 16 KB
    __shared__ __align__(16) __bf16 Bs[8192];   // 16 KB
    const int t    = threadIdx.x;
    const int w    = t >> 6;
    const int lane = t & 63;
    const int m    = lane & 15;
    const int kg   = lane >> 4;
    const int wr   = w >> 1, wc = w & 1;
    const int m0   = blockIdx.y * 128, n0 = blockIdx.x * 128;
    const int N    = gridDim.x * 128;

    f32x4 acc[4][4] = {};

    for (int k0 = 0; k0 < 1024; k0 += 64) {
        __syncthreads();   // previous iteration's frag reads complete
#pragma unroll
        for (int i = 0; i < 4; ++i) {
            const int blk = w * 4 + i;            // 0..15
            const int mt = blk >> 1, kt = blk & 1;
            const __bf16* ga = A + (size_t)(m0 + mt * 16 + m) * 1024 + k0 + kt * 32 + kg * 8;
            load_lds16(ga, &As[blk * 512]);
            const __bf16* gb = B + (size_t)(n0 + mt * 16 + m) * 1024 + k0 + kt * 32 + kg * 8;
            load_lds16(gb, &Bs[blk * 512]);
        }
        __syncthreads();   // vmcnt drain + barrier
#pragma unroll
        for (int kt = 0; kt < 2; ++kt) {
            bf16x8 af[4], bg[4];
#pragma unroll
            for (int i = 0; i < 4; ++i) {
                af[i] = *(const bf16x8*)&As[((wr * 4 + i) * 2 + kt) * 512 + lane * 8];
                bg[i] = *(const bf16x8*)&Bs[((wc * 4 + i) * 2 + kt) * 512 + lane * 8];
            }
#pragma unroll
            for (int i = 0; i < 4; ++i)
#pragma unroll
                for (int j = 0; j < 4; ++j)
                    acc[i][j] = mfma16(af[i], bg[j], acc[i][j]);
        }
    }

    // epilogue: C row = m0+wr*64+i*16+kg*4+r, col = n0+wc*64+j*16+m
#pragma unroll
    for (int i = 0; i < 4; ++i) {
        const int rb = m0 + wr * 64 + i * 16 + kg * 4;
#pragma unroll
        for (int j = 0; j < 4; ++j) {
            const int gc = n0 + wc * 64 + j * 16 + m;
#pragma unroll
            for (int r = 0; r < 4; ++r) {
                const int gr = rb + r;
                const float vv = acc[i][j][r];
                if (mode == 0) {
                    ((float*)out)[(size_t)gr * N + gc] = vv;
                } else if (mode == 1) {
                    ((__bf16*)out)[(size_t)gr * N + gc] = (__bf16)vv;
                } else {
                    const int hh = gr >> 6, dd = gr & 63;
                    const int bb = gc >> 11, ss = gc & 2047;
                    ((__bf16*)out)[(((size_t)bb * NH + hh) * DK + dd) * SEQ + ss] = (__bf16)vv;
                }
            }
        }
    }
}

// ---------------------------------------------------------------------------
// MFMA attention (unchanged structure from R2). Q,K now row-major bf16
// [B*S][1024] (head h = 128B slice per row); V stays [b][h][dk][s];
// attended output written as bf16 row-major [B*S][1024].
// ---------------------------------------------------------------------------
__global__ __launch_bounds__(512) void attn_mfma(const __bf16* __restrict__ Qp,
                                                 const __bf16* __restrict__ Kp,
                                                 const __bf16* __restrict__ Vt,
                                                 __bf16* __restrict__ att,
                                                 float* __restrict__ avg) {
    __shared__ float sc[16 * 2052 + 16];
    float* stats = &sc[16 * 2052];

    const int t    = threadIdx.x;
    const int w    = t >> 6;
    const int lane = t & 63;
    const int q0   = blockIdx.x * 16;
    const int b    = blockIdx.y;

    const int m  = lane & 15;
    const int kg = lane >> 4;

    const int tq = t >> 5;
    const int tl = t & 31;

    f32x4 avreg[16] = {};

    for (int h = 0; h < NH; ++h) {
        const __bf16* Qh = Qp + ((size_t)b * SEQ + q0) * 1024 + h * 64;
        const __bf16* Kh = Kp + (size_t)b * SEQ * 1024 + h * 64;
        const __bf16* Vh = Vt + ((size_t)b * NH + h) * DK * SEQ;

        bf16x8 a0 = *(const bf16x8*)(Qh + m * 1024 + kg * 8);
        bf16x8 a1 = *(const bf16x8*)(Qh + m * 1024 + kg * 8 + 32);

        for (int nt = w; nt < 128; nt += 8) {
            const __bf16* Kt = Kh + (size_t)(nt * 16 + m) * 1024 + kg * 8;
            bf16x8 b0 = *(const bf16x8*)(Kt);
            bf16x8 b1 = *(const bf16x8*)(Kt + 32);
            f32x4 c = {};
            c = mfma16(a0, b0, c);
            c = mfma16(a1, b1, c);
#pragma unroll
            for (int r = 0; r < 4; ++r)
                sc[(kg * 4 + r) * 2052 + nt * 16 + m] = c[r] * 0.125f;
        }
        __syncthreads();

        {
            const int q  = 2 * w + (lane >> 5);
            const int li = lane & 31;
            float* row = &sc[q * 2052];
            float mx = -1e30f;
#pragma unroll
            for (int j = 0; j < 16; ++j) {
                f32x4 v = *(const f32x4*)&row[li * 4 + j * 128];
                mx = fmaxf(mx, fmaxf(fmaxf(v[0], v[1]), fmaxf(v[2], v[3])));
            }
#pragma unroll
            for (int off = 16; off > 0; off >>= 1) mx = fmaxf(mx, __shfl_xor(mx, off, 64));
            float sum = 0.f;
#pragma unroll
            for (int j = 0; j < 16; ++j) {
                f32x4 v = *(f32x4*)&row[li * 4 + j * 128];
                v[0] = __expf(v[0] - mx); v[1] = __expf(v[1] - mx);
                v[2] = __expf(v[2] - mx); v[3] = __expf(v[3] - mx);
                *(f32x4*)&row[li * 4 + j * 128] = v;
                sum += v[0] + v[1] + v[2] + v[3];
            }
#pragma unroll
            for (int off = 16; off > 0; off >>= 1) sum += __shfl_xor(sum, off, 64);
            if (li == 0) stats[q] = 1.0f / sum;
        }
        __syncthreads();

        {
            const float s = stats[tq] * (1.0f / NH);
            const float* row = &sc[tq * 2052];
#pragma unroll
            for (int j = 0; j < 16; ++j) {
                f32x4 v = *(const f32x4*)&row[tl * 4 + j * 128];
                avreg[j] += v * s;
            }
        }

        f32x4 pv[4] = {};
        {
            const float invm = stats[m];
            const int kw = w * 256;
#pragma unroll
            for (int c8 = 0; c8 < 8; ++c8) {
                const int kb = kw + c8 * 32 + kg * 8;
                f32x4 p0 = *(const f32x4*)&sc[m * 2052 + kb];
                f32x4 p1 = *(const f32x4*)&sc[m * 2052 + kb + 4];
                bf16x8 af;
                af[0] = (__bf16)(p0[0] * invm); af[1] = (__bf16)(p0[1] * invm);
                af[2] = (__bf16)(p0[2] * invm); af[3] = (__bf16)(p0[3] * invm);
                af[4] = (__bf16)(p1[0] * invm); af[5] = (__bf16)(p1[1] * invm);
                af[6] = (__bf16)(p1[2] * invm); af[7] = (__bf16)(p1[3] * invm);
#pragma unroll
                for (int nt = 0; nt < 4; ++nt) {
                    bf16x8 bv = *(const bf16x8*)(Vh + (size_t)(nt * 16 + m) * SEQ + kb);
                    pv[nt] = mfma16(af, bv, pv[nt]);
                }
            }
        }
        __syncthreads();

#pragma unroll
        for (int nt = 0; nt < 4; ++nt)
#pragma unroll
            for (int r = 0; r < 4; ++r)
                sc[(w * 16 + kg * 4 + r) * 64 + nt * 16 + m] = pv[nt][r];
        __syncthreads();
#pragma unroll
        for (int e = 0; e < 2; ++e) {
            int idx = t + e * 512;
            int q = idx >> 6, d = idx & 63;
            float s = 0.f;
#pragma unroll
            for (int ww = 0; ww < 8; ++ww) s += sc[(ww * 16 + q) * 64 + d];
            att[((size_t)b * SEQ + q0 + q) * DMODEL + h * DK + d] = (__bf16)s;
        }
        __syncthreads();
    }

    {
        float* dst = avg + ((size_t)b * SEQ + q0 + tq) * SEQ;
#pragma unroll
        for (int j = 0; j < 16; ++j)
            *(f32x4*)&dst[tl * 4 + j * 128] = avreg[j];
    }
}

// ---------------------------------------------------------------------------
extern "C" void kernel_launch(void* const* d_in, const int* in_sizes, int n_in,
                              void* d_out, int out_size, void* d_ws, size_t ws_size,
                              hipStream_t stream) {
    const float* query = (const float*)d_in[0];
    const float* key   = (const float*)d_in[1];
    const float* value = (const float*)d_in[2];
    const float* w_q   = (const float*)d_in[3];
    const float* w_k   = (const float*)d_in[4];
    const float* w_v   = (const float*)d_in[5];
    const float* w_o   = (const float*)d_in[6];

    float* out = (float*)d_out;
    float* avg = out + (size_t)BATCH * SEQ * DMODEL;

    __bf16* Xq = (__bf16*)d_ws;            // [4096][1024]
    __bf16* Xk = Xq + 4194304;
    __bf16* Xv = Xk + 4194304;
    __bf16* Wq = Xv + 4194304;             // [1024][1024]
    __bf16* Wk = Wq + 1048576;
    __bf16* Wv = Wk + 1048576;
    __bf16* Wo = Wv + 1048576;
    __bf16* Qr = Wo + 1048576;             // [4096][1024] row-major
    __bf16* Kr = Qr + 4194304;
    __bf16* Vt = Kr + 4194304;             // [b][h][dk][s]
    __bf16* At = Xq;                       // reuse: Xq dead after Q projection

    conv_bf16<<<4096, 256, 0, stream>>>(query, key, value, w_q, w_k, w_v, w_o,
                                        Xq, Xk, Xv, Wq, Wk, Wv, Wo);

    gemm_bf16<<<dim3(8, 32), 256, 0, stream>>>(Xq, Wq, Qr, 1);   // Q row-major
    gemm_bf16<<<dim3(8, 32), 256, 0, stream>>>(Xk, Wk, Kr, 1);   // K row-major
    gemm_bf16<<<dim3(32, 8), 256, 0, stream>>>(Wv, Xv, Vt, 2);   // V^T

    attn_mfma<<<dim3(SEQ / 16, BATCH), 512, 0, stream>>>(Qr, Kr, Vt, At, avg);

    gemm_bf16<<<dim3(8, 32), 256, 0, stream>>>(At, Wo, out, 0);  // fp32 out
}